// Round 9
// baseline (267.869 us; speedup 1.0000x reference)
//
#include <hip/hip_runtime.h>
#include <hip/hip_cooperative_groups.h>
#include <math.h>

#define NEGC (-1000.0f)
namespace cg = cooperative_groups;

// Single cooperative kernel: 256 blocks x 256 threads.
// Phase A: zero adj (all blocks) + GEMM A2/B2 (blocks 0..135)   -> grid.sync
// Phase B: bilinear logits + log_sigmoid, packed  (blocks 0..63) -> grid.sync
// Phase C: sequential DP + walk + outputs (block 0, wave 0; R6-proven body)
__global__ __launch_bounds__(256, 1) void kfused(
    const float* __restrict__ seg, const float* __restrict__ vid,
    const float* __restrict__ W1, const float* __restrict__ b1,
    const float* __restrict__ W2, const float* __restrict__ b2p,
    float* __restrict__ A2, float* __restrict__ B2,
    float* __restrict__ logitsT, float* __restrict__ lsPK,
    float* __restrict__ out)
{
    __shared__ float Xs[32][64];           // phase A; reused as As in phase B
    __shared__ float Ws[32][64];           // phase A; reused as Bs in phase B
    __shared__ float w2s[256];
    __shared__ unsigned takeW[128 * 65];   // phase C: [n][wordIdx], 65-pad

    cg::grid_group grid = cg::this_grid();
    const int bid = blockIdx.x;
    const int tid = threadIdx.x;

    // ================= Phase A =================
    if (bid < 136) {
        const int tx = tid & 15, ty = tid >> 4;
        const int lr = tid >> 2;
        const int lk = (tid & 3) * 8;
        const int colBase = (bid & 3) * 64;
        const int rowBase = (bid >> 2) * 64;
        const bool isSeg = (rowBase < 128);
        const float* __restrict__ X = isSeg ? seg : vid;
        const int xRow = isSeg ? rowBase : (rowBase - 128);
        const int wOff = isSeg ? 0 : 512;

        float acc[4][4] = {};

        for (int k0 = 0; k0 < 512; k0 += 32) {
            const float* xp = X + (size_t)(xRow + lr) * 512 + (k0 + lk);
            const float4 xa = *(const float4*)xp;
            const float4 xb = *(const float4*)(xp + 4);
            const float* wp = W1 + (size_t)(colBase + lr) * 1024 + (wOff + k0 + lk);
            const float4 wa = *(const float4*)wp;
            const float4 wb = *(const float4*)(wp + 4);
            __syncthreads();
            Xs[lk + 0][lr] = xa.x; Xs[lk + 1][lr] = xa.y;
            Xs[lk + 2][lr] = xa.z; Xs[lk + 3][lr] = xa.w;
            Xs[lk + 4][lr] = xb.x; Xs[lk + 5][lr] = xb.y;
            Xs[lk + 6][lr] = xb.z; Xs[lk + 7][lr] = xb.w;
            Ws[lk + 0][lr] = wa.x; Ws[lk + 1][lr] = wa.y;
            Ws[lk + 2][lr] = wa.z; Ws[lk + 3][lr] = wa.w;
            Ws[lk + 4][lr] = wb.x; Ws[lk + 5][lr] = wb.y;
            Ws[lk + 6][lr] = wb.z; Ws[lk + 7][lr] = wb.w;
            __syncthreads();
            #pragma unroll
            for (int kk = 0; kk < 32; ++kk) {
                const float4 a4 = *(const float4*)&Xs[kk][4 * ty];
                const float4 b4 = *(const float4*)&Ws[kk][4 * tx];
                const float* a = (const float*)&a4;
                const float* b = (const float*)&b4;
                #pragma unroll
                for (int i = 0; i < 4; ++i)
                    #pragma unroll
                    for (int j = 0; j < 4; ++j)
                        acc[i][j] = fmaf(a[i], b[j], acc[i][j]);
            }
        }

        float* __restrict__ outp = (isSeg ? A2 : B2) + (size_t)xRow * 256;
        const int c = colBase + 4 * tx;
        #pragma unroll
        for (int i = 0; i < 4; ++i) {
            float4 v = make_float4(acc[i][0], acc[i][1], acc[i][2], acc[i][3]);
            if (isSeg) {
                v.x += b1[c + 0]; v.y += b1[c + 1]; v.z += b1[c + 2]; v.w += b1[c + 3];
            }
            *(float4*)(outp + (size_t)(4 * ty + i) * 256 + c) = v;
        }
    }
    {   // zero adj: 1183744 float4 = 256 blocks x 4624
        float4* out4 = (float4*)out;
        const int base = bid * 4624;
        const float4 z = make_float4(0.f, 0.f, 0.f, 0.f);
        for (int i = tid; i < 4624; i += 256) out4[base + i] = z;
    }
    grid.sync();

    // ================= Phase B =================
    if (bid < 64) {
        float (* __restrict__ As)[64] = Xs;
        float (* __restrict__ Bs)[64] = Ws;
        const int tx = tid & 15, ty = tid >> 4;
        const int lr = tid >> 2;
        const int lk = (tid & 3) * 8;
        const int nBase = (bid & 1) * 64;
        const int sBase = (bid >> 1) * 64;
        w2s[tid] = W2[tid];
        const float b2v = b2p[0];

        float acc[4][4] = {};   // [i:n][j:s]

        for (int k0 = 0; k0 < 256; k0 += 32) {
            const float* ap = A2 + (size_t)(nBase + lr) * 256 + (k0 + lk);
            const float4 aa = *(const float4*)ap;
            const float4 ab = *(const float4*)(ap + 4);
            const float* bp = B2 + (size_t)(sBase + lr) * 256 + (k0 + lk);
            const float4 ba = *(const float4*)bp;
            const float4 bb = *(const float4*)(bp + 4);
            __syncthreads();
            As[lk + 0][lr] = aa.x; As[lk + 1][lr] = aa.y;
            As[lk + 2][lr] = aa.z; As[lk + 3][lr] = aa.w;
            As[lk + 4][lr] = ab.x; As[lk + 5][lr] = ab.y;
            As[lk + 6][lr] = ab.z; As[lk + 7][lr] = ab.w;
            Bs[lk + 0][lr] = ba.x; Bs[lk + 1][lr] = ba.y;
            Bs[lk + 2][lr] = ba.z; Bs[lk + 3][lr] = ba.w;
            Bs[lk + 4][lr] = bb.x; Bs[lk + 5][lr] = bb.y;
            Bs[lk + 6][lr] = bb.z; Bs[lk + 7][lr] = bb.w;
            __syncthreads();
            #pragma unroll
            for (int kk = 0; kk < 32; ++kk) {
                const float w = w2s[k0 + kk];
                const float4 a4 = *(const float4*)&As[kk][4 * ty];
                const float4 b4 = *(const float4*)&Bs[kk][4 * tx];
                const float* a = (const float*)&a4;
                const float* b = (const float*)&b4;
                #pragma unroll
                for (int i = 0; i < 4; ++i)
                    #pragma unroll
                    for (int j = 0; j < 4; ++j)
                        acc[i][j] = fmaf(fmaxf(a[i] + b[j], 0.0f), w, acc[i][j]);
            }
        }

        const int nb = nBase + 4 * ty;
        const int s0 = sBase + 4 * tx;          // even
        float lsv[4][4];                        // [j:s-offset][i:n-offset]
        #pragma unroll
        for (int j = 0; j < 4; ++j) {
            const int s = s0 + j;
            float4 lg;
            float* lgp = (float*)&lg;
            #pragma unroll
            for (int i = 0; i < 4; ++i) {
                const float x = acc[i][j] + b2v;
                lgp[i] = x;
                lsv[j][i] = fminf(x, 0.0f) - log1pf(expf(-fabsf(x)));
            }
            *(float4*)&logitsT[(size_t)s * 128 + nb] = lg;
        }
        #pragma unroll
        for (int m = 0; m < 2; ++m) {           // two s-pairs
            const size_t base = (size_t)(s0 / 2 + m) * 256 + 2 * nb;
            #pragma unroll
            for (int q = 0; q < 2; ++q) {       // two n-pairs
                float4 v = make_float4(lsv[2 * m][2 * q],     lsv[2 * m + 1][2 * q],
                                       lsv[2 * m][2 * q + 1], lsv[2 * m + 1][2 * q + 1]);
                *(float4*)&lsPK[base + 4 * q] = v;
            }
        }
    }
    grid.sync();

    // ================= Phase C (block 0, wave 0) =================
    if (bid != 0 || tid >= 64) return;
    {
        const int lane = tid;
        const int n0 = 2 * lane, n1 = n0 + 1;
        const float4* __restrict__ ls4 = (const float4*)lsPK; // {even.n0, odd.n0, even.n1, odd.n1}

        float p0 = NEGC, p1 = NEGC;
        unsigned u0 = 2047u - (unsigned)n0;   // s - n0 (head phase)
        unsigned u1 = u0 - 1u;                // s - n1
        unsigned w0 = 0u, w1 = 0u;

        auto core = [&](float lx, float ly, float nx) {
            float c0, c1;
            unsigned long long cc;
            asm volatile(
                "v_add_f32 %[c0], %[lx], %[p1]\n\t"
                "v_add_f32 %[c1], %[ly], %[nx]\n\t"
                "v_cmp_ge_f32 vcc, %[c0], %[p0]\n\t"
                "v_cmp_ge_f32 %[cc], %[c1], %[p1]\n\t"
                "v_addc_co_u32 %[w0], vcc, %[w0], %[w0], vcc\n\t"
                "v_addc_co_u32 %[w1], %[cc], %[w1], %[w1], %[cc]\n\t"
                "v_max_f32 %[p0], %[c0], %[p0]\n\t"
                "v_max_f32 %[p1], %[c1], %[p1]\n\t"
                : [p0]"+v"(p0), [p1]"+v"(p1), [w0]"+v"(w0), [w1]"+v"(w1),
                  [c0]"=&v"(c0), [c1]"=&v"(c1), [cc]"=&s"(cc)
                : [lx]"v"(lx), [ly]"v"(ly), [nx]"v"(nx)
                : "vcc");
        };

        auto stepF = [&](float lx, float ly) { // in-band
            float nxt1 = __int_as_float(__builtin_amdgcn_update_dpp(
                0, __float_as_int(p0), 0x130 /*WAVE_SHL1*/, 0xf, 0xf, true));
            core(lx, ly, nxt1);
        };
        auto stepM = [&](float lx, float ly) { // masked (head/tail)
            float nxt1 = __int_as_float(__builtin_amdgcn_update_dpp(
                0, __float_as_int(p0), 0x130, 0xf, 0xf, true));
            core(lx, ly, nxt1);
            p0 = (u0 <= 1920u) ? p0 : NEGC;   // 0 <= s-n <= 1920 (wrap covers s<n)
            p1 = (u1 <= 1920u) ? p1 : NEGC;
            --u0; --u1;
        };

        float4 B0[4], B1[4], B2r[4], B3[4], B4[4], B5[4], B6[4], B7[4];
        int wIdx = 63;
#define LOADG(B, H) { _Pragma("unroll") \
    for (int j = 0; j < 4; ++j) B[j] = ls4[(size_t)((1023 - 4 * (H) - j) * 64 + lane)]; }
#define STEPS_F(B) { _Pragma("unroll") \
    for (int j = 0; j < 4; ++j) { stepF(B[j].y, B[j].w); stepF(B[j].x, B[j].z); } }
#define STEPS_M(B) { _Pragma("unroll") \
    for (int j = 0; j < 4; ++j) { stepM(B[j].y, B[j].w); stepM(B[j].x, B[j].z); } }
#define FLUSH { takeW[n0 * 65 + wIdx] = w0; takeW[n1 * 65 + wIdx] = w1; \
                w0 = 0u; w1 = 0u; --wIdx; }
#define BODY(SM) \
    SM(B0);  if (h +  8 < 256) LOADG(B0,  h +  8); \
    SM(B1);  if (h +  9 < 256) LOADG(B1,  h +  9); \
    SM(B2r); if (h + 10 < 256) LOADG(B2r, h + 10); \
    SM(B3);  FLUSH; if (h + 11 < 256) LOADG(B3, h + 11); \
    SM(B4);  if (h + 12 < 256) LOADG(B4,  h + 12); \
    SM(B5);  if (h + 13 < 256) LOADG(B5,  h + 13); \
    SM(B6);  if (h + 14 < 256) LOADG(B6,  h + 14); \
    SM(B7);  FLUSH; if (h + 15 < 256) LOADG(B7, h + 15);

        LOADG(B0, 0) LOADG(B1, 1) LOADG(B2r, 2) LOADG(B3, 3)
        LOADG(B4, 4) LOADG(B5, 5) LOADG(B6, 6) LOADG(B7, 7)
        // head: sub-groups 0..15 (s 2047..1920) — masked
        for (int h = 0; h < 16; h += 8) { BODY(STEPS_M) }
        // mid: sub-groups 16..239 (s 1919..128) — in-band
        for (int h = 16; h < 240; h += 8) { BODY(STEPS_F) }
        // tail: sub-groups 240..255 (s 127..0) — masked; reset u = s - n at s=127
        u0 = (unsigned)(127 - n0);
        u1 = u0 - 1u;
        for (int h = 240; h < 256; h += 8) { BODY(STEPS_M) }
#undef BODY
#undef FLUSH
#undef STEPS_M
#undef STEPS_F
#undef LOADG

        // wave-parallel walk (single wave; per-wave DS ordering suffices)
        int a0r = 0, a1r = 0, pos = 0;
        for (int n = 0; n < 128; ++n) {
            unsigned w = takeW[n * 65 + lane];
            const int wi0 = pos >> 5;
            if (lane < wi0) w = 0u;
            else if (lane == wi0) w &= (0xFFFFFFFFu << (pos & 31));
            const unsigned long long m = __ballot(w != 0u);
            if (m == 0ull) break;               // uniform
            const int fl = __builtin_ctzll(m);
            const unsigned fw = (unsigned)__builtin_amdgcn_readlane((int)w, fl);
            const int s = fl * 32 + __builtin_ctz(fw);  // wave-uniform
            if (n == n0) a0r = s;
            if (n == n1) a1r = s;
            pos = s + 1;
        }

        out[(size_t)(2048 + n0) * 2176 + a0r] = 1.0f;
        out[(size_t)(2048 + n1) * 2176 + a1r] = 1.0f;
        float sum = logitsT[(size_t)a0r * 128 + n0] + logitsT[(size_t)a1r * 128 + n1];
        #pragma unroll
        for (int off = 32; off >= 1; off >>= 1) sum += __shfl_down(sum, off);
        if (lane == 0) out[(size_t)2176 * 2176] = sum * (1.0f / 128.0f);
    }
}

extern "C" void kernel_launch(void* const* d_in, const int* in_sizes, int n_in,
                              void* d_out, int out_size, void* d_ws, size_t ws_size,
                              hipStream_t stream)
{
    const float* seg = (const float*)d_in[0];   // [128][512]
    const float* vid = (const float*)d_in[1];   // [2048][512]
    const float* W1  = (const float*)d_in[2];   // [256][1024]
    const float* b1  = (const float*)d_in[3];   // [256]
    const float* W2  = (const float*)d_in[4];   // [256]
    const float* b2  = (const float*)d_in[5];   // [1]
    float* out = (float*)d_out;
    float* ws  = (float*)d_ws;

    float* A2      = ws;             // 128*256
    float* B2      = ws + 32768;     // 2048*256
    float* logitsT = ws + 557056;    // 2048*128, [s][n]
    float* lsPK    = ws + 819200;    // 2048*128 packed [s/2][n][2]

    void* args[] = {
        (void*)&seg, (void*)&vid, (void*)&W1, (void*)&b1, (void*)&W2, (void*)&b2,
        (void*)&A2, (void*)&B2, (void*)&logitsT, (void*)&lsPK, (void*)&out
    };
    hipLaunchCooperativeKernel((const void*)kfused, dim3(256), dim3(256),
                               args, 0, stream);
}

// Round 10
// 200.034 us; speedup vs baseline: 1.3391x; 1.3391x over previous
//
#include <hip/hip_runtime.h>
#include <math.h>

#define NEGC (-1000.0f)
#define MAGICA 0x5137A9C1u
#define MAGICB 0x2468ACE1u

// ---------- KA: 136 co-resident blocks.
// Phase A: GEMM A2/B2 (R6 body) + each block zeroes 8704 float4 of adj.
// Flag sync (agent-scope release/acquire). Phase B (blocks 0..63): k2 body. ----------
__global__ __launch_bounds__(256, 1) void kA(
    const float* __restrict__ seg, const float* __restrict__ vid,
    const float* __restrict__ W1, const float* __restrict__ b1,
    const float* __restrict__ W2, const float* __restrict__ b2p,
    float* __restrict__ A2, float* __restrict__ B2,
    float* __restrict__ logitsT, float* __restrict__ lsPK,
    float* __restrict__ out, unsigned* __restrict__ flags)
{
    __shared__ float Xs[32][64];   // phase A; reused as As in phase B
    __shared__ float Ws[32][64];   // phase A; reused as Bs in phase B
    __shared__ float w2s[256];
    const int bid = blockIdx.x;
    const int tid = threadIdx.x;
    const int tx = tid & 15, ty = tid >> 4;
    const int lr = tid >> 2;
    const int lk = (tid & 3) * 8;

    // ---- Phase A: GEMM ----
    {
        const int colBase = (bid & 3) * 64;
        const int rowBase = (bid >> 2) * 64;
        const bool isSeg = (rowBase < 128);
        const float* __restrict__ X = isSeg ? seg : vid;
        const int xRow = isSeg ? rowBase : (rowBase - 128);
        const int wOff = isSeg ? 0 : 512;

        float acc[4][4] = {};

        for (int k0 = 0; k0 < 512; k0 += 32) {
            const float* xp = X + (size_t)(xRow + lr) * 512 + (k0 + lk);
            const float4 xa = *(const float4*)xp;
            const float4 xb = *(const float4*)(xp + 4);
            const float* wp = W1 + (size_t)(colBase + lr) * 1024 + (wOff + k0 + lk);
            const float4 wa = *(const float4*)wp;
            const float4 wb = *(const float4*)(wp + 4);
            __syncthreads();
            Xs[lk + 0][lr] = xa.x; Xs[lk + 1][lr] = xa.y;
            Xs[lk + 2][lr] = xa.z; Xs[lk + 3][lr] = xa.w;
            Xs[lk + 4][lr] = xb.x; Xs[lk + 5][lr] = xb.y;
            Xs[lk + 6][lr] = xb.z; Xs[lk + 7][lr] = xb.w;
            Ws[lk + 0][lr] = wa.x; Ws[lk + 1][lr] = wa.y;
            Ws[lk + 2][lr] = wa.z; Ws[lk + 3][lr] = wa.w;
            Ws[lk + 4][lr] = wb.x; Ws[lk + 5][lr] = wb.y;
            Ws[lk + 6][lr] = wb.z; Ws[lk + 7][lr] = wb.w;
            __syncthreads();
            #pragma unroll
            for (int kk = 0; kk < 32; ++kk) {
                const float4 a4 = *(const float4*)&Xs[kk][4 * ty];
                const float4 b4 = *(const float4*)&Ws[kk][4 * tx];
                const float* a = (const float*)&a4;
                const float* b = (const float*)&b4;
                #pragma unroll
                for (int i = 0; i < 4; ++i)
                    #pragma unroll
                    for (int j = 0; j < 4; ++j)
                        acc[i][j] = fmaf(a[i], b[j], acc[i][j]);
            }
        }

        float* __restrict__ outp = (isSeg ? A2 : B2) + (size_t)xRow * 256;
        const int c = colBase + 4 * tx;
        #pragma unroll
        for (int i = 0; i < 4; ++i) {
            float4 v = make_float4(acc[i][0], acc[i][1], acc[i][2], acc[i][3]);
            if (isSeg) {
                v.x += b1[c + 0]; v.y += b1[c + 1]; v.z += b1[c + 2]; v.w += b1[c + 3];
            }
            *(float4*)(outp + (size_t)(4 * ty + i) * 256 + c) = v;
        }
    }

    // ---- zero adj: 1183744 float4 = 136 blocks x 8704; 34 iters/thread exact ----
    {
        float4* out4 = (float4*)out;
        const float4 z = make_float4(0.f, 0.f, 0.f, 0.f);
        const int base = bid * 8704 + tid;
        #pragma unroll
        for (int i = 0; i < 34; ++i) out4[base + i * 256] = z;
    }

    // ---- flag sync: syncthreads drains vmcnt (stores in L2), release flushes L2 ----
    __syncthreads();
    if (tid == 0)
        __hip_atomic_store(&flags[bid], MAGICA, __ATOMIC_RELEASE, __HIP_MEMORY_SCOPE_AGENT);
    if (bid == 0) {
        if (tid < 136) {
            while (__hip_atomic_load(&flags[tid], __ATOMIC_ACQUIRE,
                                     __HIP_MEMORY_SCOPE_AGENT) != MAGICA)
                __builtin_amdgcn_s_sleep(2);
        }
        __syncthreads();
        if (tid == 0)
            __hip_atomic_store(&flags[200], MAGICB, __ATOMIC_RELEASE, __HIP_MEMORY_SCOPE_AGENT);
    }
    if (bid >= 64) return;
    if (tid == 0) {
        while (__hip_atomic_load(&flags[200], __ATOMIC_ACQUIRE,
                                 __HIP_MEMORY_SCOPE_AGENT) != MAGICB)
            __builtin_amdgcn_s_sleep(2);
    }
    __syncthreads();

    // ---- Phase B: logitsT + packed log_sigmoid (R6 k2 body) ----
    {
        float (* __restrict__ As)[64] = Xs;
        float (* __restrict__ Bs)[64] = Ws;
        const int nBase = (bid & 1) * 64;
        const int sBase = (bid >> 1) * 64;
        w2s[tid] = W2[tid];
        const float b2v = b2p[0];

        float acc[4][4] = {};   // [i:n][j:s]

        for (int k0 = 0; k0 < 256; k0 += 32) {
            const float* ap = A2 + (size_t)(nBase + lr) * 256 + (k0 + lk);
            const float4 aa = *(const float4*)ap;
            const float4 ab = *(const float4*)(ap + 4);
            const float* bp = B2 + (size_t)(sBase + lr) * 256 + (k0 + lk);
            const float4 ba = *(const float4*)bp;
            const float4 bb = *(const float4*)(bp + 4);
            __syncthreads();
            As[lk + 0][lr] = aa.x; As[lk + 1][lr] = aa.y;
            As[lk + 2][lr] = aa.z; As[lk + 3][lr] = aa.w;
            As[lk + 4][lr] = ab.x; As[lk + 5][lr] = ab.y;
            As[lk + 6][lr] = ab.z; As[lk + 7][lr] = ab.w;
            Bs[lk + 0][lr] = ba.x; Bs[lk + 1][lr] = ba.y;
            Bs[lk + 2][lr] = ba.z; Bs[lk + 3][lr] = ba.w;
            Bs[lk + 4][lr] = bb.x; Bs[lk + 5][lr] = bb.y;
            Bs[lk + 6][lr] = bb.z; Bs[lk + 7][lr] = bb.w;
            __syncthreads();
            #pragma unroll
            for (int kk = 0; kk < 32; ++kk) {
                const float w = w2s[k0 + kk];
                const float4 a4 = *(const float4*)&As[kk][4 * ty];
                const float4 b4 = *(const float4*)&Bs[kk][4 * tx];
                const float* a = (const float*)&a4;
                const float* b = (const float*)&b4;
                #pragma unroll
                for (int i = 0; i < 4; ++i)
                    #pragma unroll
                    for (int j = 0; j < 4; ++j)
                        acc[i][j] = fmaf(fmaxf(a[i] + b[j], 0.0f), w, acc[i][j]);
            }
        }

        const int nb = nBase + 4 * ty;
        const int s0 = sBase + 4 * tx;          // even
        float lsv[4][4];                        // [j:s-offset][i:n-offset]
        #pragma unroll
        for (int j = 0; j < 4; ++j) {
            const int s = s0 + j;
            float4 lg;
            float* lgp = (float*)&lg;
            #pragma unroll
            for (int i = 0; i < 4; ++i) {
                const float x = acc[i][j] + b2v;
                lgp[i] = x;
                lsv[j][i] = fminf(x, 0.0f) - log1pf(expf(-fabsf(x)));
            }
            *(float4*)&logitsT[(size_t)s * 128 + nb] = lg;
        }
        #pragma unroll
        for (int m = 0; m < 2; ++m) {           // two s-pairs
            const size_t base = (size_t)(s0 / 2 + m) * 256 + 2 * nb;
            #pragma unroll
            for (int q = 0; q < 2; ++q) {       // two n-pairs
                float4 v = make_float4(lsv[2 * m][2 * q],     lsv[2 * m + 1][2 * q],
                                       lsv[2 * m][2 * q + 1], lsv[2 * m + 1][2 * q + 1]);
                *(float4*)&lsPK[base + 4 * q] = v;
            }
        }
    }
}

// ---------- K3: R6-proven body: packed dwordx4 loads, 8-buffer rotation,
// compiler-scheduled prefetch; wave-parallel walk; outputs. ----------
__global__ __launch_bounds__(64, 1) void k3_dp(
    const float* __restrict__ lsPK, const float* __restrict__ logitsT,
    float* __restrict__ out)
{
    __shared__ unsigned takeW[128 * 65];   // [n][wordIdx], 65-pad
    __shared__ int alignSh[128];
    const int lane = threadIdx.x;
    const int n0 = 2 * lane, n1 = n0 + 1;
    const float4* __restrict__ ls4 = (const float4*)lsPK; // {even.n0, odd.n0, even.n1, odd.n1}

    float p0 = NEGC, p1 = NEGC;
    unsigned u0 = 2047u - (unsigned)n0;   // s - n0 (head phase)
    unsigned u1 = u0 - 1u;                // s - n1
    unsigned w0 = 0u, w1 = 0u;

    auto core = [&](float lx, float ly, float nx) {
        float c0, c1;
        unsigned long long cc;
        asm volatile(
            "v_add_f32 %[c0], %[lx], %[p1]\n\t"
            "v_add_f32 %[c1], %[ly], %[nx]\n\t"
            "v_cmp_ge_f32 vcc, %[c0], %[p0]\n\t"
            "v_cmp_ge_f32 %[cc], %[c1], %[p1]\n\t"
            "v_addc_co_u32 %[w0], vcc, %[w0], %[w0], vcc\n\t"
            "v_addc_co_u32 %[w1], %[cc], %[w1], %[w1], %[cc]\n\t"
            "v_max_f32 %[p0], %[c0], %[p0]\n\t"
            "v_max_f32 %[p1], %[c1], %[p1]\n\t"
            : [p0]"+v"(p0), [p1]"+v"(p1), [w0]"+v"(w0), [w1]"+v"(w1),
              [c0]"=&v"(c0), [c1]"=&v"(c1), [cc]"=&s"(cc)
            : [lx]"v"(lx), [ly]"v"(ly), [nx]"v"(nx)
            : "vcc");
    };

    auto stepF = [&](float lx, float ly) { // in-band: no range masking
        float nxt1 = __int_as_float(__builtin_amdgcn_update_dpp(
            0, __float_as_int(p0), 0x130 /*WAVE_SHL1*/, 0xf, 0xf, true));
        core(lx, ly, nxt1);
    };
    auto stepM = [&](float lx, float ly) { // masked (head/tail)
        float nxt1 = __int_as_float(__builtin_amdgcn_update_dpp(
            0, __float_as_int(p0), 0x130, 0xf, 0xf, true));
        core(lx, ly, nxt1);
        p0 = (u0 <= 1920u) ? p0 : NEGC;   // 0 <= s-n <= 1920 (wrap covers s<n)
        p1 = (u1 <= 1920u) ? p1 : NEGC;
        --u0; --u1;
    };

    float4 B0[4], B1[4], B2[4], B3[4], B4[4], B5[4], B6[4], B7[4];
#define LOADG(B, H) { _Pragma("unroll") \
    for (int j = 0; j < 4; ++j) B[j] = ls4[(size_t)((1023 - 4 * (H) - j) * 64 + lane)]; }
#define STEPS_F(B) { _Pragma("unroll") \
    for (int j = 0; j < 4; ++j) { stepF(B[j].y, B[j].w); stepF(B[j].x, B[j].z); } }
#define STEPS_M(B) { _Pragma("unroll") \
    for (int j = 0; j < 4; ++j) { stepM(B[j].y, B[j].w); stepM(B[j].x, B[j].z); } }
#define FLUSH { takeW[n0 * 65 + wIdx] = w0; takeW[n1 * 65 + wIdx] = w1; \
                w0 = 0u; w1 = 0u; --wIdx; }
#define BODY(SM) \
    SM(B0); if (h +  8 < 256) LOADG(B0, h +  8); \
    SM(B1); if (h +  9 < 256) LOADG(B1, h +  9); \
    SM(B2); if (h + 10 < 256) LOADG(B2, h + 10); \
    SM(B3); FLUSH; if (h + 11 < 256) LOADG(B3, h + 11); \
    SM(B4); if (h + 12 < 256) LOADG(B4, h + 12); \
    SM(B5); if (h + 13 < 256) LOADG(B5, h + 13); \
    SM(B6); if (h + 14 < 256) LOADG(B6, h + 14); \
    SM(B7); FLUSH; if (h + 15 < 256) LOADG(B7, h + 15);

    LOADG(B0, 0) LOADG(B1, 1) LOADG(B2, 2) LOADG(B3, 3)
    LOADG(B4, 4) LOADG(B5, 5) LOADG(B6, 6) LOADG(B7, 7)
    int wIdx = 63;
    // head: sub-groups 0..15 (s 2047..1920) — masked
    for (int h = 0; h < 16; h += 8) { BODY(STEPS_M) }
    // mid: sub-groups 16..239 (s 1919..128) — in-band
    for (int h = 16; h < 240; h += 8) { BODY(STEPS_F) }
    // tail: sub-groups 240..255 (s 127..0) — masked; reset u = s - n at s=127
    u0 = (unsigned)(127 - n0);
    u1 = u0 - 1u;
    for (int h = 240; h < 256; h += 8) { BODY(STEPS_M) }
#undef BODY
#undef FLUSH
#undef STEPS_M
#undef STEPS_F
#undef LOADG

    alignSh[n0] = 0;
    alignSh[n1] = 0;
    __syncthreads();

    // wave-parallel walk: lane holds word 'lane' of row n; ballot -> first set bit
    int pos = 0;
    for (int n = 0; n < 128; ++n) {
        unsigned w = takeW[n * 65 + lane];
        const int wi0 = pos >> 5;
        if (lane < wi0) w = 0u;
        else if (lane == wi0) w &= (0xFFFFFFFFu << (pos & 31));
        const unsigned long long m = __ballot(w != 0u);
        if (m == 0ull) break;             // uniform
        const int fl = __builtin_ctzll(m);
        const unsigned fw = (unsigned)__builtin_amdgcn_readlane((int)w, fl);
        const int s = fl * 32 + __builtin_ctz(fw);
        if (lane == 0) alignSh[n] = s;
        pos = s + 1;
    }
    __syncthreads();

    const int a0 = alignSh[n0];
    const int a1 = alignSh[n1];
    out[(size_t)(2048 + n0) * 2176 + a0] = 1.0f;
    out[(size_t)(2048 + n1) * 2176 + a1] = 1.0f;
    float sum = logitsT[(size_t)a0 * 128 + n0] + logitsT[(size_t)a1 * 128 + n1];
    #pragma unroll
    for (int off = 32; off >= 1; off >>= 1) sum += __shfl_down(sum, off);
    if (lane == 0) out[(size_t)2176 * 2176] = sum * (1.0f / 128.0f);
}

extern "C" void kernel_launch(void* const* d_in, const int* in_sizes, int n_in,
                              void* d_out, int out_size, void* d_ws, size_t ws_size,
                              hipStream_t stream)
{
    const float* seg = (const float*)d_in[0];   // [128][512]
    const float* vid = (const float*)d_in[1];   // [2048][512]
    const float* W1  = (const float*)d_in[2];   // [256][1024]
    const float* b1  = (const float*)d_in[3];   // [256]
    const float* W2  = (const float*)d_in[4];   // [256]
    const float* b2  = (const float*)d_in[5];   // [1]
    float* out = (float*)d_out;
    float* ws  = (float*)d_ws;

    float* A2      = ws;             // 128*256
    float* B2      = ws + 32768;     // 2048*256
    float* logitsT = ws + 557056;    // 2048*128, [s][n]
    float* lsPK    = ws + 819200;    // 2048*128 packed [s/2][n][2]
    unsigned* flags = (unsigned*)(ws + 1081344);  // 256 words; MAGIC != 0xAA poison

    kA<<<dim3(136), dim3(256), 0, stream>>>(seg, vid, W1, b1, W2, b2,
                                            A2, B2, logitsT, lsPK, out, flags);
    k3_dp<<<dim3(1), dim3(64), 0, stream>>>(lsPK, logitsT, out);
}

// Round 11
// 199.271 us; speedup vs baseline: 1.3442x; 1.0038x over previous
//
#include <hip/hip_runtime.h>
#include <math.h>

#define NEGC (-1000.0f)
#define MAGICA 0x5137A9C1u
#define MAGICB 0x2468ACE1u
#define MAGICC 0x13579BDFu

// ---------- KA: 136 co-resident blocks x 512 threads.
// Phase A: GEMM A2 = seg@W1a^T + b1, B2 = vid@W1b^T (64x64 tiles, 2x4/thread,
//          register-prefetched staging). Flag sync. Phase B (blocks 0..127):
//          64n x 32s logits tiles (2x2/thread), logitsT + packed lsPK. ----------
__global__ __launch_bounds__(512, 1) void kA(
    const float* __restrict__ seg, const float* __restrict__ vid,
    const float* __restrict__ W1, const float* __restrict__ b1,
    const float* __restrict__ W2, const float* __restrict__ b2p,
    float* __restrict__ A2, float* __restrict__ B2,
    float* __restrict__ logitsT, float* __restrict__ lsPK,
    unsigned* __restrict__ flags)
{
    __shared__ float Xs[32][64];   // [kk][row]; reused as As in phase B
    __shared__ float Ws[32][64];   // [kk][col]; reused as Bs in phase B
    __shared__ float w2s[256];
    const int bid = blockIdx.x;
    const int tid = threadIdx.x;
    const int tx = tid & 15;       // 0..15
    const int ty = tid >> 4;       // 0..31
    const int lr8 = tid >> 3;      // 0..63
    const int lk8 = (tid & 7) * 4; // 0,4,..,28

    // ---- Phase A: GEMM (2x4 outputs/thread) ----
    {
        const int colBase = (bid & 3) * 64;
        const int rowBase = (bid >> 2) * 64;
        const bool isSeg = (rowBase < 128);
        const float* __restrict__ X = isSeg ? seg : vid;
        const int xRow = isSeg ? rowBase : (rowBase - 128);
        const int wOff = isSeg ? 0 : 512;

        float acc[2][4] = {};
        float4 xa = *(const float4*)(X + (size_t)(xRow + lr8) * 512 + lk8);
        float4 wa = *(const float4*)(W1 + (size_t)(colBase + lr8) * 1024 + (wOff + lk8));

        for (int k0 = 0; k0 < 512; k0 += 32) {
            __syncthreads();
            Xs[lk8 + 0][lr8] = xa.x; Xs[lk8 + 1][lr8] = xa.y;
            Xs[lk8 + 2][lr8] = xa.z; Xs[lk8 + 3][lr8] = xa.w;
            Ws[lk8 + 0][lr8] = wa.x; Ws[lk8 + 1][lr8] = wa.y;
            Ws[lk8 + 2][lr8] = wa.z; Ws[lk8 + 3][lr8] = wa.w;
            __syncthreads();
            if (k0 + 32 < 512) {
                xa = *(const float4*)(X + (size_t)(xRow + lr8) * 512 + (k0 + 32 + lk8));
                wa = *(const float4*)(W1 + (size_t)(colBase + lr8) * 1024 + (wOff + k0 + 32 + lk8));
            }
            #pragma unroll
            for (int kk = 0; kk < 32; ++kk) {
                const float2 a2 = *(const float2*)&Xs[kk][2 * ty];
                const float4 b4 = *(const float4*)&Ws[kk][4 * tx];
                const float* a = (const float*)&a2;
                const float* b = (const float*)&b4;
                #pragma unroll
                for (int i = 0; i < 2; ++i)
                    #pragma unroll
                    for (int j = 0; j < 4; ++j)
                        acc[i][j] = fmaf(a[i], b[j], acc[i][j]);
            }
        }

        float* __restrict__ outp = (isSeg ? A2 : B2) + (size_t)xRow * 256;
        const int c = colBase + 4 * tx;
        #pragma unroll
        for (int i = 0; i < 2; ++i) {
            float4 v = make_float4(acc[i][0], acc[i][1], acc[i][2], acc[i][3]);
            if (isSeg) {
                v.x += b1[c + 0]; v.y += b1[c + 1]; v.z += b1[c + 2]; v.w += b1[c + 3];
            }
            *(float4*)(outp + (size_t)(2 * ty + i) * 256 + c) = v;
        }
    }

    // ---- flag sync (proven R10 shape) ----
    __syncthreads();
    if (tid == 0)
        __hip_atomic_store(&flags[bid], MAGICA, __ATOMIC_RELEASE, __HIP_MEMORY_SCOPE_AGENT);
    if (bid == 0) {
        if (tid < 136) {
            while (__hip_atomic_load(&flags[tid], __ATOMIC_ACQUIRE,
                                     __HIP_MEMORY_SCOPE_AGENT) != MAGICA)
                __builtin_amdgcn_s_sleep(2);
        }
        __syncthreads();
        if (tid == 0)
            __hip_atomic_store(&flags[200], MAGICB, __ATOMIC_RELEASE, __HIP_MEMORY_SCOPE_AGENT);
    }
    if (bid >= 128) return;
    if (tid == 0) {
        while (__hip_atomic_load(&flags[200], __ATOMIC_ACQUIRE,
                                 __HIP_MEMORY_SCOPE_AGENT) != MAGICB)
            __builtin_amdgcn_s_sleep(2);
    }
    __syncthreads();

    // ---- Phase B: 64n x 32s tile, 2x2 outputs/thread ----
    {
        const int nBase = (bid & 1) * 64;
        const int sBase = (bid >> 1) * 32;
        if (tid < 256) w2s[tid] = W2[tid];
        const float b2v = b2p[0];

        float acc[2][2] = {};   // [i:n][j:s]
        float4 aa = *(const float4*)(A2 + (size_t)(nBase + lr8) * 256 + lk8);
        float4 ba;
        if (tid < 256) ba = *(const float4*)(B2 + (size_t)(sBase + lr8) * 256 + lk8);

        for (int k0 = 0; k0 < 256; k0 += 32) {
            __syncthreads();
            Xs[lk8 + 0][lr8] = aa.x; Xs[lk8 + 1][lr8] = aa.y;
            Xs[lk8 + 2][lr8] = aa.z; Xs[lk8 + 3][lr8] = aa.w;
            if (tid < 256) {
                Ws[lk8 + 0][lr8] = ba.x; Ws[lk8 + 1][lr8] = ba.y;
                Ws[lk8 + 2][lr8] = ba.z; Ws[lk8 + 3][lr8] = ba.w;
            }
            __syncthreads();
            if (k0 + 32 < 256) {
                aa = *(const float4*)(A2 + (size_t)(nBase + lr8) * 256 + (k0 + 32 + lk8));
                if (tid < 256)
                    ba = *(const float4*)(B2 + (size_t)(sBase + lr8) * 256 + (k0 + 32 + lk8));
            }
            #pragma unroll
            for (int kk = 0; kk < 32; ++kk) {
                const float w = w2s[k0 + kk];
                const float2 a2 = *(const float2*)&Xs[kk][2 * ty];
                const float2 b2 = *(const float2*)&Ws[kk][2 * tx];
                const float* a = (const float*)&a2;
                const float* b = (const float*)&b2;
                #pragma unroll
                for (int i = 0; i < 2; ++i)
                    #pragma unroll
                    for (int j = 0; j < 2; ++j)
                        acc[i][j] = fmaf(fmaxf(a[i] + b[j], 0.0f), w, acc[i][j]);
            }
        }

        const int nb = nBase + 2 * ty;          // even
        const int s0 = sBase + 2 * tx;          // even
        float lsv[2][2];                        // [j:s][i:n]
        #pragma unroll
        for (int j = 0; j < 2; ++j) {
            float2 lg;
            float* lgp = (float*)&lg;
            #pragma unroll
            for (int i = 0; i < 2; ++i) {
                const float x = acc[i][j] + b2v;
                lgp[i] = x;
                lsv[j][i] = fminf(x, 0.0f) - log1pf(expf(-fabsf(x)));
            }
            *(float2*)&logitsT[(size_t)(s0 + j) * 128 + nb] = lg;
        }
        // lsPK[s2*256 + 2n + (s&1)]
        float4 pk = make_float4(lsv[0][0], lsv[1][0], lsv[0][1], lsv[1][1]);
        *(float4*)&lsPK[(size_t)(s0 / 2) * 256 + 2 * nb] = pk;
    }
}

// ---------- K3: block 0 (wave 0) = R9-proven DP body + walk + outputs.
// Blocks 1..255 zero the adj matrix concurrently (hidden under the serial DP),
// then release flags2; block 0 acquire-spins before writing its ones. ----------
__global__ __launch_bounds__(256, 1) void k3_dp(
    const float* __restrict__ lsPK, const float* __restrict__ logitsT,
    float* __restrict__ out, unsigned* __restrict__ flags2)
{
    __shared__ unsigned takeW[128 * 65];   // [n][wordIdx], 65-pad
    const int bid = blockIdx.x;
    const int tid = threadIdx.x;

    if (bid != 0) {
        // zero adj: 1183744 float4 over blocks 1..255 (4642 each, last +34)
        float4* out4 = (float4*)out;
        const float4 z = make_float4(0.f, 0.f, 0.f, 0.f);
        const int start = (bid - 1) * 4642;
        const int count = (bid == 255) ? 4676 : 4642;
        for (int i = tid; i < count; i += 256) out4[start + i] = z;
        __syncthreads();
        if (tid == 0)
            __hip_atomic_store(&flags2[bid], MAGICC, __ATOMIC_RELEASE, __HIP_MEMORY_SCOPE_AGENT);
        return;
    }
    if (tid >= 64) return;                 // block 0: single wave, no barriers

    const int lane = tid;
    const int n0 = 2 * lane, n1 = n0 + 1;
    const float4* __restrict__ ls4 = (const float4*)lsPK; // {even.n0, odd.n0, even.n1, odd.n1}

    float p0 = NEGC, p1 = NEGC;
    unsigned u0 = 2047u - (unsigned)n0;   // s - n0 (head phase)
    unsigned u1 = u0 - 1u;                // s - n1
    unsigned w0 = 0u, w1 = 0u;

    auto core = [&](float lx, float ly, float nx) {
        float c0, c1;
        unsigned long long cc;
        asm volatile(
            "v_add_f32 %[c0], %[lx], %[p1]\n\t"
            "v_add_f32 %[c1], %[ly], %[nx]\n\t"
            "v_cmp_ge_f32 vcc, %[c0], %[p0]\n\t"
            "v_cmp_ge_f32 %[cc], %[c1], %[p1]\n\t"
            "v_addc_co_u32 %[w0], vcc, %[w0], %[w0], vcc\n\t"
            "v_addc_co_u32 %[w1], %[cc], %[w1], %[w1], %[cc]\n\t"
            "v_max_f32 %[p0], %[c0], %[p0]\n\t"
            "v_max_f32 %[p1], %[c1], %[p1]\n\t"
            : [p0]"+v"(p0), [p1]"+v"(p1), [w0]"+v"(w0), [w1]"+v"(w1),
              [c0]"=&v"(c0), [c1]"=&v"(c1), [cc]"=&s"(cc)
            : [lx]"v"(lx), [ly]"v"(ly), [nx]"v"(nx)
            : "vcc");
    };

    auto stepF = [&](float lx, float ly) { // in-band
        float nxt1 = __int_as_float(__builtin_amdgcn_update_dpp(
            0, __float_as_int(p0), 0x130 /*WAVE_SHL1*/, 0xf, 0xf, true));
        core(lx, ly, nxt1);
    };
    auto stepM = [&](float lx, float ly) { // masked (head/tail)
        float nxt1 = __int_as_float(__builtin_amdgcn_update_dpp(
            0, __float_as_int(p0), 0x130, 0xf, 0xf, true));
        core(lx, ly, nxt1);
        p0 = (u0 <= 1920u) ? p0 : NEGC;   // 0 <= s-n <= 1920 (wrap covers s<n)
        p1 = (u1 <= 1920u) ? p1 : NEGC;
        --u0; --u1;
    };

    float4 B0[4], B1[4], B2r[4], B3[4], B4[4], B5[4], B6[4], B7[4];
    int wIdx = 63;
#define LOADG(B, H) { _Pragma("unroll") \
    for (int j = 0; j < 4; ++j) B[j] = ls4[(size_t)((1023 - 4 * (H) - j) * 64 + lane)]; }
#define STEPS_F(B) { _Pragma("unroll") \
    for (int j = 0; j < 4; ++j) { stepF(B[j].y, B[j].w); stepF(B[j].x, B[j].z); } }
#define STEPS_M(B) { _Pragma("unroll") \
    for (int j = 0; j < 4; ++j) { stepM(B[j].y, B[j].w); stepM(B[j].x, B[j].z); } }
#define FLUSH { takeW[n0 * 65 + wIdx] = w0; takeW[n1 * 65 + wIdx] = w1; \
                w0 = 0u; w1 = 0u; --wIdx; }
#define BODY(SM) \
    SM(B0);  if (h +  8 < 256) LOADG(B0,  h +  8); \
    SM(B1);  if (h +  9 < 256) LOADG(B1,  h +  9); \
    SM(B2r); if (h + 10 < 256) LOADG(B2r, h + 10); \
    SM(B3);  FLUSH; if (h + 11 < 256) LOADG(B3, h + 11); \
    SM(B4);  if (h + 12 < 256) LOADG(B4,  h + 12); \
    SM(B5);  if (h + 13 < 256) LOADG(B5,  h + 13); \
    SM(B6);  if (h + 14 < 256) LOADG(B6,  h + 14); \
    SM(B7);  FLUSH; if (h + 15 < 256) LOADG(B7, h + 15);

    LOADG(B0, 0) LOADG(B1, 1) LOADG(B2r, 2) LOADG(B3, 3)
    LOADG(B4, 4) LOADG(B5, 5) LOADG(B6, 6) LOADG(B7, 7)
    // head: sub-groups 0..15 (s 2047..1920) — masked
    for (int h = 0; h < 16; h += 8) { BODY(STEPS_M) }
    // mid: sub-groups 16..239 (s 1919..128) — in-band
    for (int h = 16; h < 240; h += 8) { BODY(STEPS_F) }
    // tail: sub-groups 240..255 (s 127..0) — masked; reset u = s - n at s=127
    u0 = (unsigned)(127 - n0);
    u1 = u0 - 1u;
    for (int h = 240; h < 256; h += 8) { BODY(STEPS_M) }
#undef BODY
#undef FLUSH
#undef STEPS_M
#undef STEPS_F
#undef LOADG

    // wave-parallel walk (single wave; per-wave DS ordering suffices)
    int a0r = 0, a1r = 0, pos = 0;
    for (int n = 0; n < 128; ++n) {
        unsigned w = takeW[n * 65 + lane];
        const int wi0 = pos >> 5;
        if (lane < wi0) w = 0u;
        else if (lane == wi0) w &= (0xFFFFFFFFu << (pos & 31));
        const unsigned long long m = __ballot(w != 0u);
        if (m == 0ull) break;               // uniform
        const int fl = __builtin_ctzll(m);
        const unsigned fw = (unsigned)__builtin_amdgcn_readlane((int)w, fl);
        const int s = fl * 32 + __builtin_ctz(fw);  // wave-uniform
        if (n == n0) a0r = s;
        if (n == n1) a1r = s;
        pos = s + 1;
    }

    // wait for all zero-blocks (they finished ~55 µs ago), then write outputs
    #pragma unroll
    for (int r = 0; r < 4; ++r) {
        const int idx = 1 + r * 64 + lane;
        if (idx <= 255) {
            while (__hip_atomic_load(&flags2[idx], __ATOMIC_ACQUIRE,
                                     __HIP_MEMORY_SCOPE_AGENT) != MAGICC)
                __builtin_amdgcn_s_sleep(2);
        }
    }

    out[(size_t)(2048 + n0) * 2176 + a0r] = 1.0f;
    out[(size_t)(2048 + n1) * 2176 + a1r] = 1.0f;
    float sum = logitsT[(size_t)a0r * 128 + n0] + logitsT[(size_t)a1r * 128 + n1];
    #pragma unroll
    for (int off = 32; off >= 1; off >>= 1) sum += __shfl_down(sum, off);
    if (lane == 0) out[(size_t)2176 * 2176] = sum * (1.0f / 128.0f);
}

extern "C" void kernel_launch(void* const* d_in, const int* in_sizes, int n_in,
                              void* d_out, int out_size, void* d_ws, size_t ws_size,
                              hipStream_t stream)
{
    const float* seg = (const float*)d_in[0];   // [128][512]
    const float* vid = (const float*)d_in[1];   // [2048][512]
    const float* W1  = (const float*)d_in[2];   // [256][1024]
    const float* b1  = (const float*)d_in[3];   // [256]
    const float* W2  = (const float*)d_in[4];   // [256]
    const float* b2  = (const float*)d_in[5];   // [1]
    float* out = (float*)d_out;
    float* ws  = (float*)d_ws;

    float* A2      = ws;             // 128*256
    float* B2      = ws + 32768;     // 2048*256
    float* logitsT = ws + 557056;    // 2048*128, [s][n]
    float* lsPK    = ws + 819200;    // 2048*128 packed [s/2][n][2]
    unsigned* flags  = (unsigned*)(ws + 1081344);  // kA sync (MAGIC != poison)
    unsigned* flags2 = (unsigned*)(ws + 1081600);  // k3 zero-done flags

    kA<<<dim3(136), dim3(512), 0, stream>>>(seg, vid, W1, b1, W2, b2,
                                            A2, B2, logitsT, lsPK, flags);
    k3_dp<<<dim3(256), dim3(256), 0, stream>>>(lsPK, logitsT, out, flags2);
}